// Round 7
// baseline (25.482 us; speedup 1.0000x reference)
//
#include <hip/hip_runtime.h>

#define BATCH 4096
#define NCLS  1024
#define DEPTH 10
#define WPB   8                      // waves per block
#define NBLOCKS (BATCH / WPB)        // 512 blocks, one sample per wave

// Single compute kernel. Per wave: one sample's hierarchical loss (same
// verified path-sum scheme as R5). Per block: LDS-reduce 8 wave losses,
// quantize to 2^-32 fixed point (loss >= 0 always: num <= den by
// construction), atomicAdd into a device-scope int64 accumulator.
// Integer atomics are order-independent => bitwise deterministic.
//
// No __threadfence (R2 showed agent-release = L2 writeback = ~22us on
// non-coherent XCD L2s). Cross-block ordering comes free: the counter
// increment is DATA-DEPENDENT on the sum-add's returned value, so a block's
// sum-add has completed at the coherence point before its count-add issues.
// count==NBLOCKS therefore implies the full sum is visible; the last block
// re-reads it with an atomic RMW (coherent), converts, writes d_out.
__global__ __launch_bounds__(WPB * 64) void hll_fused(
    const float* __restrict__ inputs,
    const int*   __restrict__ target,
    const float* __restrict__ weights,
    unsigned long long* __restrict__ sum_fx,   // zeroed each call
    unsigned int*       __restrict__ count,    // zeroed each call
    float*              __restrict__ out)
{
    const int wave = threadIdx.x >> 6;
    const int lane = threadIdx.x & 63;
    const int b = blockIdx.x * WPB + wave;

    const float4* row4 = reinterpret_cast<const float4*>(inputs + (size_t)b * NCLS);

    float4 x0 = row4[lane];
    float4 x1 = row4[64 + lane];
    float4 x2 = row4[128 + lane];
    float4 x3 = row4[192 + lane];

    const int t  = __builtin_amdgcn_readfirstlane(target[b]);  // wave-uniform
    const int ct = t >> 2;        // owning chunk
    const int st = ct >> 6;       // owning step (which of the 4 loads)
    const int lt = ct & 63;       // owning lane
    const int r  = t & 3;         // position within chunk

    const float4 xt = (st == 0) ? x0 : (st == 1) ? x1 : (st == 2) ? x2 : x3;

    const float cs0 = x0.x + x0.y + x0.z + x0.w;
    const float cs1 = x1.x + x1.y + x1.z + x1.w;
    const float cs2 = x2.x + x2.y + x2.z + x2.w;
    const float cs3 = x3.x + x3.y + x3.z + x3.w;
    const float cst = (st == 0) ? cs0 : (st == 1) ? cs1 : (st == 2) ? cs2 : cs3;

    float S[DEPTH + 1];
    S[0] = (r == 0) ? xt.x : (r == 1) ? xt.y : (r == 2) ? xt.z : xt.w;
    S[1] = (r < 2) ? (xt.x + xt.y) : (xt.z + xt.w);
    S[2] = cst;

    float a = cst;
    #pragma unroll
    for (int k = 0; k < 6; ++k) {              // S[3..8]
        a += __shfl_xor(a, 1 << k, 64);
        S[3 + k] = a;
    }

    float p = (st < 2) ? (cs0 + cs1) : (cs2 + cs3);   // owning step-pair
    float o = (st < 2) ? (cs2 + cs3) : (cs0 + cs1);   // other step-pair
    #pragma unroll
    for (int k = 0; k < 6; ++k) {
        p += __shfl_xor(p, 1 << k, 64);
        o += __shfl_xor(o, 1 << k, 64);
    }
    S[9]  = p;
    S[10] = p + o;

    float acc = 0.0f;
    #pragma unroll
    for (int j = 0; j < DEPTH; ++j) {
        const float num = S[j];
        const float den = S[j + 1];
        const float val = (num != 0.0f) ? -__logf(num / den) : num;
        acc += weights[j] * val;     // row 0 == row t (np.tile), uniform address
    }

    __shared__ float wsum[WPB];
    if (lane == lt) wsum[wave] = acc;
    __syncthreads();

    if (threadIdx.x == 0) {
        float psum = 0.0f;
        #pragma unroll
        for (int i = 0; i < WPB; ++i) psum += wsum[i];

        // fixed-point quantize (psum >= 0, < ~40; q < 2^38)
        const unsigned long long q =
            (unsigned long long)(long long)(psum * 4294967296.0);

        const unsigned long long oldsum = atomicAdd(sum_fx, q);
        // data-dependent increment (always 1: oldsum < 2^50): forces the
        // count-add to issue only after the sum-add completed coherently.
        const unsigned int inc = 1u | (unsigned int)(oldsum >> 62);
        const unsigned int oldc = atomicAdd(count, inc);

        if (oldc == NBLOCKS - 1) {
            // all sum-adds complete; coherent read via atomic RMW
            const unsigned long long tot = atomicAdd(sum_fx, 0ULL);
            const double v = (double)(long long)tot *
                             (1.0 / 4294967296.0) * (1.0 / (double)BATCH);
            out[0] = (float)v;
        }
    }
}

extern "C" void kernel_launch(void* const* d_in, const int* in_sizes, int n_in,
                              void* d_out, int out_size, void* d_ws, size_t ws_size,
                              hipStream_t stream) {
    const float* inputs  = (const float*)d_in[0];
    const int*   target  = (const int*)d_in[1];
    // d_in[2] = onehot_num, d_in[3] = onehot_den: structural, not needed.
    const float* weights = (const float*)d_in[4];

    unsigned long long* sum_fx = (unsigned long long*)d_ws;
    unsigned int*       count  = (unsigned int*)((char*)d_ws + 8);
    float*              out    = (float*)d_out;

    // zero the 12-byte accumulator region every call (ws is poisoned, not restored)
    hipMemsetAsync(d_ws, 0, 16, stream);

    hll_fused<<<NBLOCKS, WPB * 64, 0, stream>>>(inputs, target, weights,
                                                sum_fx, count, out);
}

// Round 8
// 10.942 us; speedup vs baseline: 2.3289x; 2.3289x over previous
//
#include <hip/hip_runtime.h>

#define BATCH 4096
#define NCLS  1024
#define DEPTH 10
#define NBLOCKS (BATCH / 4)   // 1024 blocks, 4 waves (one sample each) per block

// FINAL (revert to best-measured R3 structure, 11.15 us).
// Two kernels; the kernel boundary is the cheap device-wide barrier on gfx950
// (in-kernel cross-block sync measured +14..22 us: R2 fence, R7 atomics).
//
// Kernel 1: one sample per wave. Lane l holds row elements [l*16, l*16+16).
// Aligned block sums along target t's root path:
//   S[0..4]  : within the owning lane's 16-element segment (t wave-uniform).
//   S[5..10] : __shfl_xor butterfly; after step k each lane holds its aligned
//              2^(k+1)-lane-group sum — lane t>>4 carries the true path.
// Loss = sum_j w[j] * -log(S[j]/S[j+1]); weights rows identical (np.tile),
// so row 0 is read through a uniform address (early s_loads, no target dep).
__global__ __launch_bounds__(256) void hll_per_block(
    const float* __restrict__ inputs,
    const int*   __restrict__ target,
    const float* __restrict__ weights,
    float*       __restrict__ partials)
{
    const int wave = threadIdx.x >> 6;
    const int lane = threadIdx.x & 63;
    const int b = blockIdx.x * 4 + wave;

    const int t = __builtin_amdgcn_readfirstlane(target[b]);   // wave-uniform
    const float4* row = reinterpret_cast<const float4*>(inputs + (size_t)b * NCLS);

    float4 x0 = row[lane * 4 + 0];
    float4 x1 = row[lane * 4 + 1];
    float4 x2 = row[lane * 4 + 2];
    float4 x3 = row[lane * 4 + 3];

    const int s = t & 15;
    const int q = s >> 2;
    const int r = s & 3;

    float4 xq = (q == 0) ? x0 : (q == 1) ? x1 : (q == 2) ? x2 : x3;

    float S[DEPTH + 1];
    S[0] = (r == 0) ? xq.x : (r == 1) ? xq.y : (r == 2) ? xq.z : xq.w;
    S[1] = (r < 2) ? (xq.x + xq.y) : (xq.z + xq.w);
    S[2] = xq.x + xq.y + xq.z + xq.w;

    const float q0 = x0.x + x0.y + x0.z + x0.w;
    const float q1 = x1.x + x1.y + x1.z + x1.w;
    const float q2 = x2.x + x2.y + x2.z + x2.w;
    const float q3 = x3.x + x3.y + x3.z + x3.w;
    S[3] = (q < 2) ? (q0 + q1) : (q2 + q3);
    S[4] = q0 + q1 + q2 + q3;

    float ssum = S[4];
    #pragma unroll
    for (int k = 0; k < 6; ++k) {
        ssum += __shfl_xor(ssum, 1 << k, 64);
        S[5 + k] = ssum;
    }

    float acc = 0.0f;
    #pragma unroll
    for (int j = 0; j < DEPTH; ++j) {
        const float num = S[j];
        const float den = S[j + 1];
        const float val = (num != 0.0f) ? -__logf(num / den) : num;
        acc += weights[j] * val;      // row 0 == row t (np.tile), uniform address
    }

    __shared__ float wsum[4];
    if (lane == (t >> 4)) wsum[wave] = acc;
    __syncthreads();
    if (threadIdx.x == 0)
        partials[blockIdx.x] = wsum[0] + wsum[1] + wsum[2] + wsum[3];
}

// Kernel 2: single-wave deterministic mean over the 1024 block partials.
__global__ __launch_bounds__(64) void hll_reduce(
    const float* __restrict__ partials,
    float*       __restrict__ out)
{
    const int lane = threadIdx.x;
    const float4* p4 = reinterpret_cast<const float4*>(partials);
    float s = 0.0f;
    #pragma unroll
    for (int i = 0; i < NBLOCKS / 256; ++i) {   // 4 x float4 per lane
        float4 v = p4[lane + i * 64];
        s += v.x + v.y + v.z + v.w;
    }
    #pragma unroll
    for (int k = 0; k < 6; ++k)
        s += __shfl_xor(s, 1 << k, 64);
    if (lane == 0) out[0] = s * (1.0f / (float)BATCH);
}

extern "C" void kernel_launch(void* const* d_in, const int* in_sizes, int n_in,
                              void* d_out, int out_size, void* d_ws, size_t ws_size,
                              hipStream_t stream) {
    const float* inputs  = (const float*)d_in[0];
    const int*   target  = (const int*)d_in[1];
    // d_in[2] = onehot_num, d_in[3] = onehot_den: structural, not needed.
    const float* weights = (const float*)d_in[4];

    float* partials = (float*)d_ws;   // NBLOCKS floats, fully rewritten each call
    float* out      = (float*)d_out;

    hll_per_block<<<NBLOCKS, 256, 0, stream>>>(inputs, target, weights, partials);
    hll_reduce<<<1, 64, 0, stream>>>(partials, out);
}